// Round 17
// baseline (52.723 us; speedup 1.0000x reference)
//
#include <hip/hip_runtime.h>

typedef _Float16 f16x8 __attribute__((ext_vector_type(8)));
typedef _Float16 f16x4 __attribute__((ext_vector_type(4)));
typedef _Float16 f16x2 __attribute__((ext_vector_type(2)));
typedef float    f32x4 __attribute__((ext_vector_type(4)));

// ---- global ws layout (halfword units), produced by precompute ----
#define PRE_OFF   0
#define PRE_SZ    (2 * 170 * 64)
#define W1G_OFF   (PRE_OFF + PRE_SZ)          // 21760 (128 hw)
#define W2P_OFF   (W1G_OFF + 2 * 64)          // 21888 (4096 hw)
#define W3P_OFF   (W2P_OFF + 2 * 32 * 64)     // 25984 (1024 hw)
#define WFR_OFF   (W3P_OFF + 2 * 16 * 32)     // 27008 (320 hw)
#define H16_END   (WFR_OFF + 320)             // 27328
#define FOFF      H16_END
#define B2P_F     0
#define B3P_F     (B2P_F + 2 * 32)            // 64  (+32) -> 96 floats

// ---- LDS layout (halfword units) ----
// Round-17: pre-table NOT staged -- its 20 gathers/wave-chunk move to the
// idle VMEM pipe (global ws, L2-resident 43.5 KB). LDS holds only the
// fragment tables: w2 [64][72], w3 [32][40], w1g [2][64], wfr [10][40],
// smf[96]f. Total 12.8 KB -> staging is ~1/4 the old cost and the DS pipe
// (the busiest shared resource, ~52 reads/wave-chunk + 3.4M conflict cycles)
// drops to ~32 conflict-light reads.
#define L_W1    0
#define L_W2    128
#define L_W3    (L_W2 + 64 * 72)              // 4736
#define L_WFR   (L_W3 + 32 * 40)              // 6016
#define L_END   (L_WFR + 10 * 40)             // 6416 hw = 12832 B

__global__ void precompute(const float* __restrict__ emb,
                           const float* __restrict__ W1a, const float* __restrict__ b1a,
                           const float* __restrict__ W2a, const float* __restrict__ b2a,
                           const float* __restrict__ W3a, const float* __restrict__ b3a,
                           const float* __restrict__ W1b, const float* __restrict__ b1b,
                           const float* __restrict__ W2b, const float* __restrict__ b2b,
                           const float* __restrict__ W3b, const float* __restrict__ b3b,
                           const float* __restrict__ Wf,
                           _Float16* __restrict__ ws16)
{
    const int team = blockIdx.y;
    const float* __restrict__ W1 = team ? W1b : W1a;
    const float* __restrict__ B1 = team ? b1b : b1a;
    const float* __restrict__ W2 = team ? W2b : W2a;
    const float* __restrict__ B2 = team ? b2b : b2a;
    const float* __restrict__ W3 = team ? W3b : W3a;
    const float* __restrict__ B3 = team ? b3b : b3a;
    float* __restrict__ wsf = (float*)(ws16 + FOFF);
    const int tid = threadIdx.x;

    if (blockIdx.x < 170) {
        const int cc = blockIdx.x;
        const int k = tid;
        float v = 0.0f;
        if (k < 50) {
            v = B1[k];
            for (int d = 0; d < 50; ++d)
                v = fmaf(W1[k * 51 + d], emb[cc * 50 + d], v);
        }
        ws16[PRE_OFF + team * 170 * 64 + cc * 64 + k] = (_Float16)v;
    } else {
        for (int i = tid; i < 64; i += 64)
            ws16[W1G_OFF + team * 64 + i] = (_Float16)((i < 50) ? W1[i * 51 + 50] : 0.0f);
        for (int i = tid; i < 32 * 64; i += 64) {
            const int m = i >> 6, k = i & 63;
            ws16[W2P_OFF + team * 2048 + i] =
                (_Float16)((m < 25 && k < 50) ? W2[m * 50 + k] : 0.0f);
        }
        for (int i = tid; i < 16 * 32; i += 64) {
            const int t = i >> 5, m = i & 31;
            ws16[W3P_OFF + team * 512 + i] =
                (_Float16)((t < 10 && m < 25) ? W3[t * 25 + m] : 0.0f);
        }
        for (int i = tid; i < 5 * 2 * 16; i += 64) {
            const int s = i >> 5, r = (i >> 4) & 1, k = i & 15;
            ws16[WFR_OFF + team * 160 + i] =
                (_Float16)((k < 10) ? Wf[r * 100 + team * 50 + s * 10 + k] : 0.0f);
        }
        for (int i = tid; i < 32; i += 64) wsf[B2P_F + team * 32 + i] = (i < 25) ? B2[i] : 0.0f;
        for (int i = tid; i < 16; i += 64) wsf[B3P_F + team * 16 + i] = (i < 10) ? B3[i] : 0.0f;
    }
}

__device__ __forceinline__ f16x8 hfma8(f16x8 a, f16x8 b, f16x8 c) {
    return __builtin_elementwise_fma(a, b, c);
}
__device__ __forceinline__ f16x8 hrelu8(f16x8 a) {
    const f16x8 z = {0, 0, 0, 0, 0, 0, 0, 0};
    return __builtin_elementwise_max(a, z);
}
__device__ __forceinline__ f16x2 pkrtz(float a, float b) {
    return __builtin_bit_cast(f16x2, __builtin_amdgcn_cvt_pkrtz(a, b));
}

// Round-17 = round-16 body with the pre-row gathers moved to the VMEM pipe.
// r12/r13/r16 plateau diagnosis: VALU ~17us and the CU-shared LDS pipe
// ~16-22us (incl. 5.5us bank-conflict serialization) barely overlap -> 33us.
// The VMEM pipe sits at 1.4%. Splitting: per-slot pre-rows load from GLOBAL
// ws (L2-resident, 1-slot-ahead prefetch pipeline kept, fully unrolled --
// unlike r14's rolled serial version), fragments stay in LDS. DS traffic
// -40%, pre bank-conflicts gone, LDS 12.8 KB (staging /4). waves_per_eu(4,4)
// = proven no-spill point; occupancy stays ~24 waves/CU (VGPR-bound).
__global__ __launch_bounds__(512)
__attribute__((amdgpu_waves_per_eu(4, 4)))
void match_predict(const float* __restrict__ feat, const _Float16* __restrict__ ws16,
                   const float* __restrict__ bf, float* __restrict__ out, int nB)
{
    __shared__ __align__(16) _Float16 sm16[L_END];
    __shared__ __align__(16) float    smf[96];

    const int tid = threadIdx.x;
    const int l  = tid & 63;
    const int c  = l & 15;          // sample column
    const int g  = l >> 4;          // k-chunk / row group
    const int wv = tid >> 6;

    // ---- stage fragment tables only (12.8 KB), once per block ----
    for (int i = tid; i < 16; i += 512)
        *(f16x8*)(sm16 + L_W1 + i * 8) = *(const f16x8*)(ws16 + W1G_OFF + i * 8);
    for (int i = tid; i < 64 * 8; i += 512) {             // w2: 64 -> 72 stride
        const int r = i >> 3, ch = i & 7;
        *(f16x8*)(sm16 + L_W2 + r * 72 + ch * 8) =
            *(const f16x8*)(ws16 + W2P_OFF + r * 64 + ch * 8);
    }
    for (int i = tid; i < 32 * 4; i += 512) {             // w3: 32 -> 40 stride
        const int r = i >> 2, ch = i & 3;
        *(f16x8*)(sm16 + L_W3 + r * 40 + ch * 8) =
            *(const f16x8*)(ws16 + W3P_OFF + r * 32 + ch * 8);
    }
    for (int i = tid; i < 40; i += 512) {                 // wfr: 32 -> 40 stride
        const int ts = i >> 2, ch = i & 3;
        *(f16x8*)(sm16 + L_WFR + ts * 40 + ch * 8) =
            *(const f16x8*)(ws16 + WFR_OFF + ts * 32 + ch * 8);
    }
    for (int i = tid; i < 24; i += 512)
        *(f32x4*)(smf + i * 4) = *(const f32x4*)((const float*)(ws16 + FOFF) + i * 4);
    __syncthreads();

    const float bf0 = bf[0], bf1 = bf[1];
    const int nchunks = (nB + 127) >> 7;

    for (int ck = blockIdx.x; ck < nchunks; ck += gridDim.x) {
        const int base = ck * 128 + wv * 16;
        if (base >= nB) continue;
        const int sample = base + c;
        const int sEff   = (sample < nB) ? sample : (nB - 1);

        const float4* f4 = reinterpret_cast<const float4*>(feat + (size_t)sEff * 12);
        const float4 v0 = f4[0], v1 = f4[1], v2 = f4[2];
        const float fr[12] = {v0.x, v0.y, v0.z, v0.w, v1.x, v1.y, v1.z, v1.w,
                              v2.x, v2.y, v2.z, v2.w};

        f32x4 aout = {0.f, 0.f, 0.f, 0.f};

        // prime the pre-row pipeline with slot 0 (GLOBAL reads, VMEM pipe)
        f16x8 pc0, pc1;
        {
            const int ci0 = (int)fr[2];
            const _Float16* p = ws16 + PRE_OFF + ci0 * 64;
            pc0 = *(const f16x8*)(p + g * 8);
            pc1 = *(const f16x8*)(p + 32 + g * 8);
        }

        #pragma unroll
        for (int team = 0; team < 2; ++team) {
            f16x8 w2A[2][2];
            #pragma unroll
            for (int mt = 0; mt < 2; ++mt)
                #pragma unroll
                for (int kf = 0; kf < 2; ++kf)
                    w2A[mt][kf] = *(const f16x8*)(sm16 + L_W2
                                     + (team * 32 + mt * 16 + c) * 72 + kf * 32 + g * 8);
            const f16x4 w3A0 = *(const f16x4*)(sm16 + L_W3 + (team * 16 + c) * 40 + 4 * g);
            const f16x4 w3A1 = *(const f16x4*)(sm16 + L_W3 + (team * 16 + c) * 40 + 16 + 4 * g);
            const f16x8 w1gA = *(const f16x8*)(sm16 + L_W1 + team * 64 + g * 8);
            const f16x8 w1gB = *(const f16x8*)(sm16 + L_W1 + team * 64 + 32 + g * 8);
            f16x4 wfrA[5];
            #pragma unroll
            for (int s = 0; s < 5; ++s)
                wfrA[s] = *(const f16x4*)(sm16 + L_WFR + (team * 5 + s) * 40
                                          + (c & 1) * 16 + 4 * g);
            const f32x4 b2lo = *(const f32x4*)(smf + B2P_F + team * 32 + 4 * g);
            const f32x4 b2hi = *(const f32x4*)(smf + B2P_F + team * 32 + 16 + 4 * g);
            const f32x4 b3v  = *(const f32x4*)(smf + B3P_F + team * 16 + 4 * g);
            const _Float16 glh = (_Float16)fr[team];
            const f16x8 glv = {glh, glh, glh, glh, glh, glh, glh, glh};

            #pragma unroll
            for (int s5 = 0; s5 < 5; ++s5) {
                const int slot = team * 5 + s5;

                // prefetch next slot's pre-rows from GLOBAL (VMEM pipe; the
                // slot's ~300cy of MFMA+VALU below hides the L2 latency)
                f16x8 pn0 = pc0, pn1 = pc1;
                if (slot < 9) {
                    const int cin = (int)fr[3 + slot];
                    const int tn = (slot + 1) / 5;          // literal after unroll
                    const _Float16* pn = ws16 + PRE_OFF + (tn * 170 + cin) * 64;
                    pn0 = *(const f16x8*)(pn + g * 8);
                    pn1 = *(const f16x8*)(pn + 32 + g * 8);
                }

                // h1^T B-frag (lane (c,g) = h1[sample c][k = chunk*32 + g*8 + i])
                const f16x8 h10 = hrelu8(hfma8(w1gA, glv, pc0));
                const f16x8 h11 = hrelu8(hfma8(w1gB, glv, pc1));

                // layer 2: h2^T[m][c] = W2 . h1^T, b2 as C-in
                f32x4 a0 = b2lo, a1 = b2hi;
                a0 = __builtin_amdgcn_mfma_f32_16x16x32_f16(w2A[0][0], h10, a0, 0, 0, 0);
                a0 = __builtin_amdgcn_mfma_f32_16x16x32_f16(w2A[0][1], h11, a0, 0, 0, 0);
                a1 = __builtin_amdgcn_mfma_f32_16x16x32_f16(w2A[1][0], h10, a1, 0, 0, 0);
                a1 = __builtin_amdgcn_mfma_f32_16x16x32_f16(w2A[1][1], h11, a1, 0, 0, 0);

                // relu + pack: K=16 B-frag slots k=4g+q
                const f16x2 p00 = pkrtz(fmaxf(a0[0], 0.f), fmaxf(a0[1], 0.f));
                const f16x2 p01 = pkrtz(fmaxf(a0[2], 0.f), fmaxf(a0[3], 0.f));
                const f16x2 p10 = pkrtz(fmaxf(a1[0], 0.f), fmaxf(a1[1], 0.f));
                const f16x2 p11 = pkrtz(fmaxf(a1[2], 0.f), fmaxf(a1[3], 0.f));
                const f16x4 b3t0 = {p00.x, p00.y, p01.x, p01.y};
                const f16x4 b3t1 = {p10.x, p10.y, p11.x, p11.y};

                // layer 3: h3^T[t][c] = W3 . h2^T, b3 as C-in
                f32x4 a3 = b3v;
                a3 = __builtin_amdgcn_mfma_f32_16x16x16f16(w3A0, b3t0, a3, 0, 0, 0);
                a3 = __builtin_amdgcn_mfma_f32_16x16x16f16(w3A1, b3t1, a3, 0, 0, 0);

                // final layer MFMA: B = relu(h3), A = Wf rows, C accumulates
                const f16x2 q0 = pkrtz(fmaxf(a3[0], 0.f), fmaxf(a3[1], 0.f));
                const f16x2 q1 = pkrtz(fmaxf(a3[2], 0.f), fmaxf(a3[3], 0.f));
                const f16x4 h3f = {q0.x, q0.y, q1.x, q1.y};
                aout = __builtin_amdgcn_mfma_f32_16x16x16f16(wfrA[s5], h3f, aout, 0, 0, 0);

                pc0 = pn0; pc1 = pn1;
            }
        }

        if (g == 0 && sample < nB) {
            reinterpret_cast<float2*>(out)[sample] =
                make_float2(aout[0] + bf0, aout[1] + bf1);
        }
    }
}

extern "C" void kernel_launch(void* const* d_in, const int* in_sizes, int n_in,
                              void* d_out, int out_size, void* d_ws, size_t ws_size,
                              hipStream_t stream) {
    const float* feat = (const float*)d_in[0];
    const float* emb  = (const float*)d_in[1];
    const float* W1a  = (const float*)d_in[2];
    const float* b1a  = (const float*)d_in[3];
    const float* W2a  = (const float*)d_in[4];
    const float* b2a  = (const float*)d_in[5];
    const float* W3a  = (const float*)d_in[6];
    const float* b3a  = (const float*)d_in[7];
    const float* W1b  = (const float*)d_in[8];
    const float* b1b  = (const float*)d_in[9];
    const float* W2b  = (const float*)d_in[10];
    const float* b2b  = (const float*)d_in[11];
    const float* W3b  = (const float*)d_in[12];
    const float* b3b  = (const float*)d_in[13];
    const float* Wf   = (const float*)d_in[14];
    const float* bf   = (const float*)d_in[15];
    float* out = (float*)d_out;
    _Float16* ws16 = (_Float16*)d_ws;

    const int nB = in_sizes[0] / 12;

    precompute<<<dim3(171, 2), 64, 0, stream>>>(emb,
        W1a, b1a, W2a, b2a, W3a, b3a,
        W1b, b1b, W2b, b2b, W3b, b3b, Wf, ws16);

    const int nchunks = (nB + 127) / 128;
    int blocks = 768;                               // persistent, co-resident
    if (blocks > nchunks) blocks = nchunks;
    match_predict<<<blocks, 512, 0, stream>>>(feat, ws16, bf, out, nB);
}

// Round 18
// 34.937 us; speedup vs baseline: 1.5091x; 1.5091x over previous
//
#include <hip/hip_runtime.h>

typedef _Float16 f16x8 __attribute__((ext_vector_type(8)));
typedef _Float16 f16x4 __attribute__((ext_vector_type(4)));
typedef _Float16 f16x2 __attribute__((ext_vector_type(2)));
typedef float    f32x4 __attribute__((ext_vector_type(4)));

// ---- global ws layout (halfword units), produced by precompute ----
#define PRE_OFF   0
#define PRE_SZ    (2 * 170 * 64)
#define W1G_OFF   (PRE_OFF + PRE_SZ)          // 21760 (128 hw)
#define W2P_OFF   (W1G_OFF + 2 * 64)          // 21888 (4096 hw)
#define W3P_OFF   (W2P_OFF + 2 * 32 * 64)     // 25984 (1024 hw)
#define WFR_OFF   (W3P_OFF + 2 * 16 * 32)     // 27008 (320 hw)
#define H16_END   (WFR_OFF + 320)             // 27328
#define FOFF      H16_END
#define B2P_F     0
#define B3P_F     (B2P_F + 2 * 32)            // 64  (+32) -> 96 floats

// ---- LDS layout (halfword units) ----
// pre [340][56], w2 [64][72], w3 [32][40], w1g [2][64], wfr [10][40], smf[96]f
// Total 51.3 KB -> 3 blocks/CU (r16-validated).
#define LP_STR  56
#define L_PRE   0
#define L_W1    (340 * LP_STR)                // 19040
#define L_W2    (L_W1 + 128)                  // 19168
#define L_W3    (L_W2 + 64 * 72)              // 23776
#define L_WFR   (L_W3 + 32 * 40)              // 25056
#define L_END   (L_WFR + 10 * 40)             // 25456 hw = 50912 B

__global__ void precompute(const float* __restrict__ emb,
                           const float* __restrict__ W1a, const float* __restrict__ b1a,
                           const float* __restrict__ W2a, const float* __restrict__ b2a,
                           const float* __restrict__ W3a, const float* __restrict__ b3a,
                           const float* __restrict__ W1b, const float* __restrict__ b1b,
                           const float* __restrict__ W2b, const float* __restrict__ b2b,
                           const float* __restrict__ W3b, const float* __restrict__ b3b,
                           const float* __restrict__ Wf,
                           _Float16* __restrict__ ws16)
{
    const int team = blockIdx.y;
    const float* __restrict__ W1 = team ? W1b : W1a;
    const float* __restrict__ B1 = team ? b1b : b1a;
    const float* __restrict__ W2 = team ? W2b : W2a;
    const float* __restrict__ B2 = team ? b2b : b2a;
    const float* __restrict__ W3 = team ? W3b : W3a;
    const float* __restrict__ B3 = team ? b3b : b3a;
    float* __restrict__ wsf = (float*)(ws16 + FOFF);
    const int tid = threadIdx.x;

    if (blockIdx.x < 170) {
        const int cc = blockIdx.x;
        const int k = tid;
        float v = 0.0f;
        if (k < 50) {
            v = B1[k];
            for (int d = 0; d < 50; ++d)
                v = fmaf(W1[k * 51 + d], emb[cc * 50 + d], v);
        }
        ws16[PRE_OFF + team * 170 * 64 + cc * 64 + k] = (_Float16)v;
    } else {
        for (int i = tid; i < 64; i += 64)
            ws16[W1G_OFF + team * 64 + i] = (_Float16)((i < 50) ? W1[i * 51 + 50] : 0.0f);
        for (int i = tid; i < 32 * 64; i += 64) {
            const int m = i >> 6, k = i & 63;
            ws16[W2P_OFF + team * 2048 + i] =
                (_Float16)((m < 25 && k < 50) ? W2[m * 50 + k] : 0.0f);
        }
        for (int i = tid; i < 16 * 32; i += 64) {
            const int t = i >> 5, m = i & 31;
            ws16[W3P_OFF + team * 512 + i] =
                (_Float16)((t < 10 && m < 25) ? W3[t * 25 + m] : 0.0f);
        }
        for (int i = tid; i < 5 * 2 * 16; i += 64) {
            const int s = i >> 5, r = (i >> 4) & 1, k = i & 15;
            ws16[WFR_OFF + team * 160 + i] =
                (_Float16)((k < 10) ? Wf[r * 100 + team * 50 + s * 10 + k] : 0.0f);
        }
        for (int i = tid; i < 32; i += 64) wsf[B2P_F + team * 32 + i] = (i < 25) ? B2[i] : 0.0f;
        for (int i = tid; i < 16; i += 64) wsf[B3P_F + team * 16 + i] = (i < 10) ? B3[i] : 0.0f;
    }
}

__device__ __forceinline__ f16x8 hfma8(f16x8 a, f16x8 b, f16x8 c) {
    return __builtin_elementwise_fma(a, b, c);
}
__device__ __forceinline__ f16x8 hrelu8(f16x8 a) {
    const f16x8 z = {0, 0, 0, 0, 0, 0, 0, 0};
    return __builtin_elementwise_max(a, z);
}
__device__ __forceinline__ f16x4 hrelu4(f16x4 a) {
    const f16x4 z = {0, 0, 0, 0};
    return __builtin_elementwise_max(a, z);
}
__device__ __forceinline__ f16x2 pkrtz(float a, float b) {
    return __builtin_bit_cast(f16x2, __builtin_amdgcn_cvt_pkrtz(a, b));
}

// Round-18 = round-16 base + dependency-chain breaking in the slot body:
//  (a) each 2-deep MFMA pair -> two INDEPENDENT MFMAs (Cin = bias / 0) + one
//      vector add: 7 dependent stages/slot -> 5.
//  (b) relu in f16 domain AFTER pkrtz (v_pk_max_f16 on pairs): -6 VALU/slot.
//      Identical math: cvt is monotone, cvt(0)=0.
//  (c) aout split by slot parity: the 10-deep serial final-MFMA chain -> 2x5.
// r16-proven settings kept: LDS-resident tables (51.3 KB, 3 blocks/CU),
// waves_per_eu(4,4) no-spill point, full unroll, 768 persistent blocks.
__global__ __launch_bounds__(512)
__attribute__((amdgpu_waves_per_eu(4, 4)))
void match_predict(const float* __restrict__ feat, const _Float16* __restrict__ ws16,
                   const float* __restrict__ bf, float* __restrict__ out, int nB)
{
    __shared__ __align__(16) _Float16 sm16[L_END];
    __shared__ __align__(16) float    smf[96];

    const int tid = threadIdx.x;
    const int l  = tid & 63;
    const int c  = l & 15;          // sample column
    const int g  = l >> 4;          // k-chunk / row group
    const int wv = tid >> 6;

    // ---- stage tables: global ws -> LDS, once per block ----
    for (int i = tid; i < 340 * 7; i += 512) {            // pre: 64 -> 56 stride
        const int r = i / 7, ch = i - r * 7;
        *(f16x8*)(sm16 + L_PRE + r * LP_STR + ch * 8) =
            *(const f16x8*)(ws16 + PRE_OFF + r * 64 + ch * 8);
    }
    for (int i = tid; i < 16; i += 512)
        *(f16x8*)(sm16 + L_W1 + i * 8) = *(const f16x8*)(ws16 + W1G_OFF + i * 8);
    for (int i = tid; i < 64 * 8; i += 512) {             // w2: 64 -> 72 stride
        const int r = i >> 3, ch = i & 7;
        *(f16x8*)(sm16 + L_W2 + r * 72 + ch * 8) =
            *(const f16x8*)(ws16 + W2P_OFF + r * 64 + ch * 8);
    }
    for (int i = tid; i < 32 * 4; i += 512) {             // w3: 32 -> 40 stride
        const int r = i >> 2, ch = i & 3;
        *(f16x8*)(sm16 + L_W3 + r * 40 + ch * 8) =
            *(const f16x8*)(ws16 + W3P_OFF + r * 32 + ch * 8);
    }
    for (int i = tid; i < 40; i += 512) {                 // wfr: 32 -> 40 stride
        const int ts = i >> 2, ch = i & 3;
        *(f16x8*)(sm16 + L_WFR + ts * 40 + ch * 8) =
            *(const f16x8*)(ws16 + WFR_OFF + ts * 32 + ch * 8);
    }
    for (int i = tid; i < 24; i += 512)
        *(f32x4*)(smf + i * 4) = *(const f32x4*)((const float*)(ws16 + FOFF) + i * 4);
    __syncthreads();

    const float bf0 = bf[0], bf1 = bf[1];
    const int nchunks = (nB + 127) >> 7;
    const f32x4 zero4 = {0.f, 0.f, 0.f, 0.f};

    for (int ck = blockIdx.x; ck < nchunks; ck += gridDim.x) {
        const int base = ck * 128 + wv * 16;
        if (base >= nB) continue;
        const int sample = base + c;
        const int sEff   = (sample < nB) ? sample : (nB - 1);

        const float4* f4 = reinterpret_cast<const float4*>(feat + (size_t)sEff * 12);
        const float4 v0 = f4[0], v1 = f4[1], v2 = f4[2];
        const float fr[12] = {v0.x, v0.y, v0.z, v0.w, v1.x, v1.y, v1.z, v1.w,
                              v2.x, v2.y, v2.z, v2.w};

        f32x4 aoutE = zero4, aoutO = zero4;   // final-layer C split by slot parity

        // prime the pre-row pipeline with slot 0
        f16x8 pc0, pc1;
        {
            const int ci0 = (int)fr[2];
            const _Float16* p = sm16 + L_PRE + ci0 * LP_STR;
            pc0 = *(const f16x8*)(p + g * 8);
            pc1 = *(const f16x8*)(p + 32 + g * 8);
        }

        #pragma unroll
        for (int team = 0; team < 2; ++team) {
            f16x8 w2A[2][2];
            #pragma unroll
            for (int mt = 0; mt < 2; ++mt)
                #pragma unroll
                for (int kf = 0; kf < 2; ++kf)
                    w2A[mt][kf] = *(const f16x8*)(sm16 + L_W2
                                     + (team * 32 + mt * 16 + c) * 72 + kf * 32 + g * 8);
            const f16x4 w3A0 = *(const f16x4*)(sm16 + L_W3 + (team * 16 + c) * 40 + 4 * g);
            const f16x4 w3A1 = *(const f16x4*)(sm16 + L_W3 + (team * 16 + c) * 40 + 16 + 4 * g);
            const f16x8 w1gA = *(const f16x8*)(sm16 + L_W1 + team * 64 + g * 8);
            const f16x8 w1gB = *(const f16x8*)(sm16 + L_W1 + team * 64 + 32 + g * 8);
            f16x4 wfrA[5];
            #pragma unroll
            for (int s = 0; s < 5; ++s)
                wfrA[s] = *(const f16x4*)(sm16 + L_WFR + (team * 5 + s) * 40
                                          + (c & 1) * 16 + 4 * g);
            const f32x4 b2lo = *(const f32x4*)(smf + B2P_F + team * 32 + 4 * g);
            const f32x4 b2hi = *(const f32x4*)(smf + B2P_F + team * 32 + 16 + 4 * g);
            const f32x4 b3v  = *(const f32x4*)(smf + B3P_F + team * 16 + 4 * g);
            const _Float16 glh = (_Float16)fr[team];
            const f16x8 glv = {glh, glh, glh, glh, glh, glh, glh, glh};

            #pragma unroll
            for (int s5 = 0; s5 < 5; ++s5) {
                const int slot = team * 5 + s5;

                // issue next slot's pre-row reads before this slot's compute
                f16x8 pn0 = pc0, pn1 = pc1;
                if (slot < 9) {
                    const int cin = (int)fr[3 + slot];
                    const int tn = (slot + 1) / 5;          // literal after unroll
                    const _Float16* pn = sm16 + L_PRE + (tn * 170 + cin) * LP_STR;
                    pn0 = *(const f16x8*)(pn + g * 8);
                    pn1 = *(const f16x8*)(pn + 32 + g * 8);
                }

                // h1^T B-frag
                const f16x8 h10 = hrelu8(hfma8(w1gA, glv, pc0));
                const f16x8 h11 = hrelu8(hfma8(w1gB, glv, pc1));

                // layer 2: two INDEPENDENT MFMAs per tile, one add (chain 2->1)
                f32x4 a0  = __builtin_amdgcn_mfma_f32_16x16x32_f16(w2A[0][0], h10, b2lo,  0, 0, 0);
                f32x4 a0x = __builtin_amdgcn_mfma_f32_16x16x32_f16(w2A[0][1], h11, zero4, 0, 0, 0);
                f32x4 a1  = __builtin_amdgcn_mfma_f32_16x16x32_f16(w2A[1][0], h10, b2hi,  0, 0, 0);
                f32x4 a1x = __builtin_amdgcn_mfma_f32_16x16x32_f16(w2A[1][1], h11, zero4, 0, 0, 0);
                a0 = a0 + a0x;
                a1 = a1 + a1x;

                // pack (RTZ) then relu in f16 domain (v_pk_max_f16)
                const f16x2 p00 = pkrtz(a0[0], a0[1]);
                const f16x2 p01 = pkrtz(a0[2], a0[3]);
                const f16x2 p10 = pkrtz(a1[0], a1[1]);
                const f16x2 p11 = pkrtz(a1[2], a1[3]);
                const f16x4 b3t0 = hrelu4((f16x4){p00.x, p00.y, p01.x, p01.y});
                const f16x4 b3t1 = hrelu4((f16x4){p10.x, p10.y, p11.x, p11.y});

                // layer 3: two independent MFMAs, one add
                f32x4 a3  = __builtin_amdgcn_mfma_f32_16x16x16f16(w3A0, b3t0, b3v,   0, 0, 0);
                f32x4 a3x = __builtin_amdgcn_mfma_f32_16x16x16f16(w3A1, b3t1, zero4, 0, 0, 0);
                a3 = a3 + a3x;

                // final layer MFMA into parity-split accumulator
                const f16x2 q0 = pkrtz(a3[0], a3[1]);
                const f16x2 q1 = pkrtz(a3[2], a3[3]);
                const f16x4 h3f = hrelu4((f16x4){q0.x, q0.y, q1.x, q1.y});
                if (slot & 1)
                    aoutO = __builtin_amdgcn_mfma_f32_16x16x16f16(wfrA[s5], h3f, aoutO, 0, 0, 0);
                else
                    aoutE = __builtin_amdgcn_mfma_f32_16x16x16f16(wfrA[s5], h3f, aoutE, 0, 0, 0);

                pc0 = pn0; pc1 = pn1;
            }
        }

        const f32x4 aout = aoutE + aoutO;
        if (g == 0 && sample < nB) {
            reinterpret_cast<float2*>(out)[sample] =
                make_float2(aout[0] + bf0, aout[1] + bf1);
        }
    }
}

extern "C" void kernel_launch(void* const* d_in, const int* in_sizes, int n_in,
                              void* d_out, int out_size, void* d_ws, size_t ws_size,
                              hipStream_t stream) {
    const float* feat = (const float*)d_in[0];
    const float* emb  = (const float*)d_in[1];
    const float* W1a  = (const float*)d_in[2];
    const float* b1a  = (const float*)d_in[3];
    const float* W2a  = (const float*)d_in[4];
    const float* b2a  = (const float*)d_in[5];
    const float* W3a  = (const float*)d_in[6];
    const float* b3a  = (const float*)d_in[7];
    const float* W1b  = (const float*)d_in[8];
    const float* b1b  = (const float*)d_in[9];
    const float* W2b  = (const float*)d_in[10];
    const float* b2b  = (const float*)d_in[11];
    const float* W3b  = (const float*)d_in[12];
    const float* b3b  = (const float*)d_in[13];
    const float* Wf   = (const float*)d_in[14];
    const float* bf   = (const float*)d_in[15];
    float* out = (float*)d_out;
    _Float16* ws16 = (_Float16*)d_ws;

    const int nB = in_sizes[0] / 12;

    precompute<<<dim3(171, 2), 64, 0, stream>>>(emb,
        W1a, b1a, W2a, b2a, W3a, b3a,
        W1b, b1b, W2b, b2b, W3b, b3b, Wf, ws16);

    const int nchunks = (nB + 127) / 128;
    int blocks = 768;                               // 3 blocks/CU, all co-resident
    if (blocks > nchunks) blocks = nchunks;
    match_predict<<<blocks, 512, 0, stream>>>(feat, ws16, bf, out, nB);
}